// Round 3
// baseline (687.548 us; speedup 1.0000x reference)
//
#include <hip/hip_runtime.h>

// ---------------------------------------------------------------------------
// KAN 2-layer forward, round 3.
// Round 2 structure (full-width BN, split-K=2, packed activation, BK=32,
// stride-40 LDS, global prefetch) with ONE fix: partial-C stride is now the
// workspace slot size (B*512 elems) for BOTH layers, so split-K partial 1
// lands exactly at the p1 slot the reducers read. Round 2 passed B*256 for
// layer 2 -> out_reduce summed poisoned memory -> half of layer-2's K lost.
// ---------------------------------------------------------------------------

typedef short s16x8 __attribute__((ext_vector_type(8)));  // 8 bf16 = 4 VGPRs
typedef float f32x4 __attribute__((ext_vector_type(4)));

__device__ __forceinline__ unsigned pk2(float lo, float hi) {
  // two fp32 -> packed bf16 pair, RNE (inputs finite)
  unsigned a = __float_as_uint(lo), b = __float_as_uint(hi);
  a = a + 0x7fffu + ((a >> 16) & 1u);
  b = b + 0x7fffu + ((b >> 16) & 1u);
  return (a >> 16) | (b & 0xffff0000u);
}

__device__ __forceinline__ unsigned short f2bf(float f) {
  unsigned u = __float_as_uint(f);
  unsigned r = u + 0x7fffu + ((u >> 16) & 1u);
  return (unsigned short)(r >> 16);
}

// silu + 6 cubic B-spline bases (uniform extended grid, u = 1.5x+4.5, knots
// at u=0..9; hat recursion verified vs reference in round 1), packed bf16x8:
// [silu, b3_0..b3_5, 0]
__device__ __forceinline__ uint4 kan_act8(float x) {
  float e = __expf(-x);
  float s = x * __builtin_amdgcn_rcpf(1.0f + e);
  float u = fmaf(x, 1.5f, 4.5f);
  float b1[8];
#pragma unroll
  for (int j = 0; j < 8; ++j)
    b1[j] = fmaxf(0.0f, 1.0f - fabsf(u - (float)(j + 1)));
  float uh = u * 0.5f;
  float b2[7];
#pragma unroll
  for (int j = 0; j < 7; ++j)
    b2[j] = (uh - 0.5f * (float)j) * b1[j] + (0.5f * (float)(j + 3) - uh) * b1[j + 1];
  float ut = u * (1.0f / 3.0f);
  float b3[6];
#pragma unroll
  for (int j = 0; j < 6; ++j)
    b3[j] = (ut - (1.0f / 3.0f) * (float)j) * b2[j] +
            ((1.0f / 3.0f) * (float)(j + 4) - ut) * b2[j + 1];
  uint4 r;
  r.x = pk2(s, b3[0]);
  r.y = pk2(b3[1], b3[2]);
  r.z = pk2(b3[3], b3[4]);
  r.w = pk2(b3[5], 0.0f);
  return r;
}

// Pack weights: Wp[n][i*8+t] bf16; t=0 base_w, t=1..6 spline_w*scaler, t=7 0.
__global__ __launch_bounds__(256) void prep_w(
    const float* __restrict__ base_w, const float* __restrict__ spline_w,
    const float* __restrict__ scaler, short* __restrict__ Wp,
    int F, int Nvalid) {
  int i = blockIdx.x * 256 + threadIdx.x;
  int n = blockIdx.y;
  if (i >= F) return;
  s16x8 v;
#pragma unroll
  for (int k = 0; k < 8; ++k) v[k] = 0;
  if (n < Nvalid) {
    int idx = n * F + i;
    float sc = scaler[idx];
    v[0] = (short)f2bf(base_w[idx]);
#pragma unroll
    for (int k = 0; k < 6; ++k) v[1 + k] = (short)f2bf(spline_w[idx * 6 + k] * sc);
  }
  *(s16x8*)&Wp[((size_t)n * F + i) * 8] = v;
}

// Fused-activation split-K GEMM, full output width in one block column.
// BM=128, BN in {512,256}, BK=32 (4 features), 512 threads = 8 waves (2m x 4n),
// wave tile 64 x (BN/4). blockIdx.y = K-part; partial C -> Cp + y*pstride,
// pstride = workspace slot size in elements (NOT a function of BN).
// LDS row stride 40 shorts: banks (20r+4c) mod 32 -> <=2-way (free), 16B chunks.
template <int BN>
__global__ __launch_bounds__(512, 2) void kan_gemm_sk(
    const float* __restrict__ X, const short* __restrict__ W,
    float* __restrict__ Cp, int F, int span, long long pstride) {
  constexpr int LDT = 40;
  constexpr int NTN = BN / 64;   // n-tiles per wave
  constexpr int BJ  = BN / 128;  // B staging rows per thread
  __shared__ __align__(16) short As[128 * LDT];
  __shared__ __align__(16) short Bs[BN * LDT];

  const int t    = threadIdx.x;
  const int lane = t & 63;
  const int w    = t >> 6;
  const int m0   = blockIdx.x * 128;
  const int f0   = blockIdx.y * span;
  const int K8   = F * 8;  // W row stride (shorts)

  const int wrow = (w >> 2) * 64;
  const int wcol = (w & 3) * (BN / 4);
  const int mrow = lane & 15;
  const int q    = lane >> 4;

  int a_off[4], b_off[NTN];
#pragma unroll
  for (int it = 0; it < 4; ++it)
    a_off[it] = (wrow + it * 16 + mrow) * LDT + q * 8;
#pragma unroll
  for (int jt = 0; jt < NTN; ++jt)
    b_off[jt] = (wcol + jt * 16 + mrow) * LDT + q * 8;

  // staging: thread -> (row sr, feature-chunk sc) ; A rows 0..127, B rows sr+128j
  const int sr = t >> 2;
  const int sc = t & 3;
  const float* xp = X + (size_t)(m0 + sr) * F + f0 + sc;
  const short* wp = W + (size_t)sr * K8 + (size_t)(f0 + sc) * 8;
  const int aw = sr * LDT + sc * 8;

  f32x4 acc[4][NTN] = {};

  const int ksteps = span >> 2;
  float xv = *xp;
  uint4 wv[BJ];
#pragma unroll
  for (int j = 0; j < BJ; ++j)
    wv[j] = *(const uint4*)&wp[(size_t)(j * 128) * K8];

  for (int ks = 0; ks < ksteps; ++ks) {
    uint4 av = kan_act8(xv);
    *(uint4*)&As[aw] = av;
#pragma unroll
    for (int j = 0; j < BJ; ++j)
      *(uint4*)&Bs[aw + j * 128 * LDT] = wv[j];
    __syncthreads();

    // prefetch next step's globals; vmcnt wait lands at next act -> hidden
    if (ks + 1 < ksteps) {
      xv = xp[(ks + 1) * 4];
#pragma unroll
      for (int j = 0; j < BJ; ++j)
        wv[j] = *(const uint4*)&wp[(size_t)(j * 128) * K8 + (size_t)(ks + 1) * 32];
    }

    s16x8 af[4], bfr[NTN];
#pragma unroll
    for (int it = 0; it < 4; ++it)
      af[it] = *(const s16x8*)&As[a_off[it]];
#pragma unroll
    for (int jt = 0; jt < NTN; ++jt)
      bfr[jt] = *(const s16x8*)&Bs[b_off[jt]];
#pragma unroll
    for (int a = 0; a < 4; ++a)
#pragma unroll
      for (int b = 0; b < NTN; ++b)
        acc[a][b] = __builtin_amdgcn_mfma_f32_16x16x32_bf16(
            af[a], bfr[b], acc[a][b], 0, 0, 0);
    __syncthreads();
  }

  // C/D layout: col = lane&15, row = quad*4 + reg (verified r1)
  float* cpt = Cp + (size_t)blockIdx.y * (size_t)pstride;
#pragma unroll
  for (int a = 0; a < 4; ++a) {
#pragma unroll
    for (int b = 0; b < NTN; ++b) {
      int col = wcol + b * 16 + mrow;
#pragma unroll
      for (int r = 0; r < 4; ++r) {
        int row = m0 + wrow + a * 16 + q * 4 + r;
        cpt[(size_t)row * BN + col] = acc[a][b][r];
      }
    }
  }
}

// h = LayerNorm(p0 + p1) over D=512, one wave per row.
__global__ __launch_bounds__(256) void ln_reduce(
    const float* __restrict__ p0, const float* __restrict__ p1,
    float* __restrict__ h, const float* __restrict__ gamma,
    const float* __restrict__ beta, int nparts) {
  int lane = threadIdx.x & 63;
  int wv   = threadIdx.x >> 6;
  int row  = blockIdx.x * 4 + wv;
  size_t base = (size_t)row * 512 + lane * 8;
  f32x4 v0 = *(const f32x4*)(p0 + base);
  f32x4 v1 = *(const f32x4*)(p0 + base + 4);
  if (nparts == 2) {
    f32x4 u0 = *(const f32x4*)(p1 + base);
    f32x4 u1 = *(const f32x4*)(p1 + base + 4);
#pragma unroll
    for (int k = 0; k < 4; ++k) { v0[k] += u0[k]; v1[k] += u1[k]; }
  }
  float s = 0.f, s2 = 0.f;
#pragma unroll
  for (int k = 0; k < 4; ++k) { s += v0[k] + v1[k]; s2 += v0[k]*v0[k] + v1[k]*v1[k]; }
#pragma unroll
  for (int m = 32; m >= 1; m >>= 1) {
    s  += __shfl_xor(s,  m, 64);
    s2 += __shfl_xor(s2, m, 64);
  }
  float mean = s * (1.0f / 512.0f);
  float var  = s2 * (1.0f / 512.0f) - mean * mean;
  float rstd = rsqrtf(var + 1e-5f);
  const f32x4 g0 = *(const f32x4*)(gamma + lane * 8);
  const f32x4 g1 = *(const f32x4*)(gamma + lane * 8 + 4);
  const f32x4 be0 = *(const f32x4*)(beta + lane * 8);
  const f32x4 be1 = *(const f32x4*)(beta + lane * 8 + 4);
#pragma unroll
  for (int k = 0; k < 4; ++k) {
    v0[k] = (v0[k] - mean) * rstd * g0[k] + be0[k];
    v1[k] = (v1[k] - mean) * rstd * g1[k] + be1[k];
  }
  *(f32x4*)(h + base) = v0;
  *(f32x4*)(h + base + 4) = v1;
}

// out[b][c<229] = p0[b][c] (+ p1[b][c]) with 256-wide padded partials.
__global__ __launch_bounds__(256) void out_reduce(
    const float* __restrict__ p0, const float* __restrict__ p1,
    float* __restrict__ out, int nparts) {
  int idx = blockIdx.x * 256 + threadIdx.x;
  int row = idx >> 8;
  int c   = idx & 255;
  float v = p0[idx];
  if (nparts == 2) v += p1[idx];
  if (c < 229) out[(size_t)row * 229 + c] = v;
}

extern "C" void kernel_launch(void* const* d_in, const int* in_sizes, int n_in,
                              void* d_out, int out_size, void* d_ws, size_t ws_size,
                              hipStream_t stream) {
  const float* x         = (const float*)d_in[0];
  const float* base_w1   = (const float*)d_in[1];
  const float* spline_w1 = (const float*)d_in[2];
  const float* scaler1   = (const float*)d_in[3];
  const float* ln_gamma  = (const float*)d_in[4];
  const float* ln_beta   = (const float*)d_in[5];
  const float* base_w2   = (const float*)d_in[6];
  const float* spline_w2 = (const float*)d_in[7];
  const float* scaler2   = (const float*)d_in[8];
  float* out = (float*)d_out;

  const int B = 16384, D_IN = 1280, D_HID = 512, D_OUT = 229;

  // ws layout: W1p | W2p | h | p0 | p1
  const size_t szW1 = (size_t)D_HID * D_IN * 8 * 2;   // 10,485,760
  const size_t szW2 = (size_t)256 * D_HID * 8 * 2;    //  2,097,152
  const size_t szH  = (size_t)B * D_HID * 4;          // 33,554,432
  const size_t szP  = (size_t)B * 512 * 4;            // 33,554,432 (slot size)
  char* ws = (char*)d_ws;
  short* W1p = (short*)ws;
  short* W2p = (short*)(ws + szW1);
  float* h   = (float*)(ws + szW1 + szW2);
  float* p0  = (float*)(ws + szW1 + szW2 + szH);
  float* p1  = (float*)(ws + szW1 + szW2 + szH + szP);

  const int parts = (ws_size >= szW1 + szW2 + szH + 2 * szP) ? 2 : 1;
  // partial stride in ELEMENTS = slot size, same for both layers (r2 bugfix)
  const long long pstride = (long long)(szP / 4);

  prep_w<<<dim3(D_IN / 256, D_HID), 256, 0, stream>>>(
      base_w1, spline_w1, scaler1, W1p, D_IN, D_HID);
  prep_w<<<dim3(D_HID / 256, 256), 256, 0, stream>>>(
      base_w2, spline_w2, scaler2, W2p, D_HID, D_OUT);

  // layer 1: (16384 x 1280) -> (16384 x 512)
  kan_gemm_sk<512><<<dim3(B / 128, parts), 512, 0, stream>>>(
      x, W1p, p0, D_IN, D_IN / parts, pstride);

  ln_reduce<<<dim3(B / 4), 256, 0, stream>>>(p0, p1, h, ln_gamma, ln_beta, parts);

  // layer 2: (16384 x 512) -> (16384 x 256 padded)
  kan_gemm_sk<256><<<dim3(B / 128, parts), 512, 0, stream>>>(
      h, W2p, p0, D_HID, D_HID / parts, pstride);

  out_reduce<<<dim3(B * 256 / 256), 256, 0, stream>>>(p0, p1, out, parts);
}